// Round 1
// baseline (497.984 us; speedup 1.0000x reference)
//
#include <hip/hip_runtime.h>
#include <hip/hip_fp16.h>

// CTC forward loss. B=64, T=2000, C=128 (blank=127), Lmax=200, S=401.
// FUSED producer-consumer single kernel (previously pack_kernel -> ctc_alpha
// serialized on one stream; pack's ~105us is now hidden under the 148us
// serial alpha recursion, which only uses 64 CUs / 3% of HBM BW).
//   blocks 0..63   : producer for batch b (4 waves, 256 thr): softmax + gather
//                    into W (identical math/layout to old pack_kernel, labels
//                    hoisted per block). 32 phases x 64 rows; publishes a
//                    per-batch step watermark with an agent-scope RELEASE
//                    store (vmcnt drain + buffer_wbl2 -> MALL coherent point)
//                    at phases 4,8,...,28,31.
//   blocks 64..127 : consumer (1 wave/b): unchanged alpha recursion (linear
//                    domain + pow2 exponent tracking, DPP halos, double-
//                    buffered global_load_lds chunks, raw vmcnt waits), gated
//                    on the watermark once per 8-chunk group (256 steps) with
//                    agent-scope ACQUIRE polls, always at vmcnt==0 points.
// Watermarks live at W + 64*SB, zeroed by hipMemsetAsync each launch (so a
// re-poisoned workspace cannot fake "ready"). Total footprint 66,052,352 B
// (BLANKB shrunk 8192->8064) < 66,060,288 B proven by the 2-kernel version.

#define LOG2E 1.44269504088896340736f
#define LN2F  0.69314718055994530942f

namespace {

constexpr int Bc = 64, Tc = 2000, Cc = 128, Lmaxc = 200;
constexpr int NPAIR = Tc / 2;                // 1000
constexpr int PAIRB = 1024;                  // bytes per pair (64 lanes x 16)
constexpr int BLANKB = 8064;                 // f32 blank region (1999*4 used)
constexpr size_t SB = (size_t)NPAIR * PAIRB + BLANKB;  // per-batch stride
constexpr size_t FLAGS_OFF = (size_t)Bc * SB;          // 64 watermark ints
constexpr int CHP = 16;                      // pairs per chunk
constexpr int CHB = CHP * PAIRB;             // 16 KB

typedef const __attribute__((address_space(1))) void* gas_ptr;
typedef __attribute__((address_space(3))) void* las_ptr;

__device__ __forceinline__ float dpp_shr1_f(float x) {  // lane i <- i-1, lane0 <- 0
  return __int_as_float(
      __builtin_amdgcn_update_dpp(0, __float_as_int(x), 0x138, 0xF, 0xF, true));
}
__device__ __forceinline__ int dpp_shr1_i(int x) {
  return __builtin_amdgcn_update_dpp(0, x, 0x138, 0xF, 0xF, true);
}
template <int CTRL>
__device__ __forceinline__ float dpp_add(float v) {
  return v + __int_as_float(
      __builtin_amdgcn_update_dpp(0, __float_as_int(v), CTRL, 0xF, 0xF, true));
}
__device__ __forceinline__ float wave_sum_bcast(float v) {  // full-wave sum
  v = dpp_add<0x111>(v);
  v = dpp_add<0x112>(v);
  v = dpp_add<0x114>(v);
  v = dpp_add<0x118>(v);
  v = dpp_add<0x142>(v);
  v = dpp_add<0x143>(v);
  return __int_as_float(__builtin_amdgcn_readlane(__float_as_int(v), 63));
}

__global__ __launch_bounds__(256, 1) void ctc_fused_kernel(
    const float* __restrict__ y, char* __restrict__ W,
    const int* __restrict__ y_true, const int* __restrict__ in_len,
    const int* __restrict__ lab_len, float* __restrict__ out) {
  __shared__ __align__(16) char bufs[2][CHB];      // 32 KB (consumer)
  __shared__ __align__(16) float blk_s[2048];      // 8 KB  (consumer)

  if (blockIdx.x < Bc) {
    // ------------------------- producer: batch b -------------------------
    const int b = blockIdx.x;
    const int wv = threadIdx.x >> 6, lane = threadIdx.x & 63;
    const int* labs = y_true + b * Lmaxc;
    int base = 4 * lane;
    if (base > Lmaxc - 4) base = Lmaxc - 4;
    const int4 L = *(const int4*)(labs + base);
    auto fix = [&](int v, int idx) {
      int r = (idx > Lmaxc - 1) ? L.w : v;   // labc clamp: idx>199 -> labs[199]
      return r < 0 ? 0 : r;                  // ref maps padded -1 -> 0
    };
    const int c0 = fix(L.x, 4 * lane), c1 = fix(L.y, 4 * lane + 1);
    const int c2 = fix(L.z, 4 * lane + 2), c3 = fix(L.w, 4 * lane + 3);
    char* Wb = W + (size_t)b * SB;
    int* wmp = (int*)(W + FLAGS_OFF) + b;
    const float* yrow = y + (size_t)b * Tc * Cc + 2 * lane;

    for (int p = 0; p < 32; ++p) {
      const int t0 = p * 64 + wv * 16;
#pragma unroll 4
      for (int i = 0; i < 16; ++i) {
        const int t = t0 + i;                // wave-uniform
        if (t >= 1 && t < Tc) {
          const float2 yy = *(const float2*)(yrow + (size_t)t * Cc);
          float e0 = exp2f(fminf(yy.x * LOG2E, 50.f));
          float e1 = exp2f(fminf(yy.y * LOG2E, 50.f));
          const float rs = 1.0f / wave_sum_bcast(e0 + e1);
          unsigned q2 =
              __builtin_bit_cast(unsigned, __floats2half2_rn(e0 * rs, e1 * rs));
          unsigned g0 = (unsigned)__builtin_amdgcn_ds_bpermute((c0 >> 1) << 2, (int)q2);
          unsigned g1 = (unsigned)__builtin_amdgcn_ds_bpermute((c1 >> 1) << 2, (int)q2);
          unsigned g2 = (unsigned)__builtin_amdgcn_ds_bpermute((c2 >> 1) << 2, (int)q2);
          unsigned g3 = (unsigned)__builtin_amdgcn_ds_bpermute((c3 >> 1) << 2, (int)q2);
          unsigned h0 = (c0 & 1) ? (g0 >> 16) : (g0 & 0xFFFFu);
          unsigned h1 = (c1 & 1) ? (g1 >> 16) : (g1 & 0xFFFFu);
          unsigned h2 = (c2 & 1) ? (g2 >> 16) : (g2 & 0xFFFFu);
          unsigned h3 = (c3 & 1) ? (g3 >> 16) : (g3 & 0xFFFFu);
          const int pr = (t - 1) >> 1, sl = 1 - (t & 1);  // odd t -> slot 0
          *(uint2*)(Wb + pr * PAIRB + lane * 16 + sl * 8) =
              make_uint2(h0 | (h1 << 16), h2 | (h3 << 16));
          if (lane == 63)  // blank = class 127 prob, pre-converted f32
            *(float*)(Wb + (size_t)NPAIR * PAIRB + (size_t)(t - 1) * 4) = e1 * rs;
        }
      }
      __syncthreads();  // drains each wave's vmem before the release fence
      if (threadIdx.x == 0 && ((p > 0 && (p & 3) == 0) || p == 31)) {
        int v = 64 * (p + 1) - 1;            // steps <= v are written
        if (v > Tc - 1) v = Tc - 1;
        __hip_atomic_store(wmp, v, __ATOMIC_RELEASE, __HIP_MEMORY_SCOPE_AGENT);
      }
    }
    return;
  }

  // ------------------------- consumer: batch b -------------------------
  if (threadIdx.x >= 64) return;
  const int b = blockIdx.x - Bc, lane = threadIdx.x;
  int len = in_len[b];
  len = len < 1 ? 1 : (len > Tc ? Tc : len);
  const int ll = lab_len[b];
  const int* labs = y_true + b * Lmaxc;
  auto labc = [&](int l) -> int {
    int lc = l < 0 ? 0 : (l > Lmaxc - 1 ? Lmaxc - 1 : l);
    int c = labs[lc];
    return c < 0 ? 0 : c;
  };
  const int c0i = labc(4 * lane), c1i = labc(4 * lane + 1);
  const int c2i = labc(4 * lane + 2), c3i = labc(4 * lane + 3);
  const int cm1 = labc(4 * lane - 1), cm2 = labc(4 * lane - 2);
  const float sk0 = (4 * lane >= 1 && c0i != cm1) ? 1.f : 0.f;
  const float sk1 = (c1i != c0i) ? 1.f : 0.f;
  const float sk2 = (c2i != c1i) ? 1.f : 0.f;
  const float sk3 = (c3i != c2i) ? 1.f : 0.f;
  const float skH = (lane >= 1 && cm1 != cm2) ? 1.f : 0.f;
  const int lane16 = lane * 16;

  const char* Wb = W + (size_t)b * SB;
  int* wmp = (int*)(W + FLAGS_OFF) + b;
  auto wait_wm = [&](int need) {   // bounded spin: hang-proof; acquire = inv
    for (int k = 0; k < (1 << 19); ++k) {
      if (__hip_atomic_load(wmp, __ATOMIC_ACQUIRE, __HIP_MEMORY_SCOPE_AGENT) >= need)
        break;
      __builtin_amdgcn_s_sleep(2);
    }
  };
  auto load_pairs = [&](int bi, int k) {
#pragma unroll
    for (int j = 0; j < CHP; ++j) {
      unsigned off = (unsigned)(CHP * k + j) * PAIRB + lane16;
      __builtin_amdgcn_global_load_lds((gas_ptr)(Wb + off),
                                       (las_ptr)(&bufs[bi][j * PAIRB]), 16, 0, 0);
    }
  };
  auto load_blank_region = [&](int r) {  // 1 KB = blanks for 256 steps
    __builtin_amdgcn_global_load_lds(
        (gas_ptr)(Wb + NPAIR * PAIRB + r * 1024 + lane16),
        (las_ptr)((char*)blk_s + r * 1024), 16, 0, 0);
  };

  float a0 = 0.f, a1 = 0.f, a2 = 0.f, a3 = 0.f;
  float a4 = 0.f, a5 = 0.f, a6 = 0.f, a7 = 0.f;
  int E = 0;
  {  // seed from y row t=0 directly (row 0 is not packed)
    const float* y0 = y + (size_t)b * Tc * Cc + 2 * lane;
    float e0 = exp2f(fminf(y0[0] * LOG2E, 50.f));
    float e1 = exp2f(fminf(y0[1] * LOG2E, 50.f));
    const float rs = 1.0f / wave_sum_bcast(e0 + e1);
    int l0 = labs[0];
    l0 = l0 < 0 ? 0 : l0;
    float ev = (l0 & 1) ? e1 : e0;
    float q0 = __int_as_float(__builtin_amdgcn_readlane(__float_as_int(ev), l0 >> 1)) * rs;
    float qb = __int_as_float(__builtin_amdgcn_readlane(__float_as_int(e1), 63)) * rs;
    if (lane == 0) { a0 = qb; a1 = q0; }
  }
  float s7d = dpp_shr1_f(a7), s6d = dpp_shr1_f(a6), s5d = dpp_shr1_f(a5);
  int epd = 0;
  float corr = (lane == 0) ? 0.f : 1.f;

  // pair-round: 2 lattice steps from one 16B slot + f32 blank pair
  auto round2 = [&](uint4 rw, float2 bl, bool renorm) {
    float2 aLo = __half22float2(*(__half2*)&rw.x);
    float2 aHi = __half22float2(*(__half2*)&rw.y);
    float2 bLo = __half22float2(*(__half2*)&rw.z);
    float2 bHi = __half22float2(*(__half2*)&rw.w);
    const float qbA = bl.x, qbB = bl.y;
    const float qhA = dpp_shr1_f(aHi.y);  // halo label prob (VALU pipe)
    const float w7 = s7d * corr, w6 = s6d * corr, w5 = s5d * corr;
    const float hA = (w7 + w6 + skH * w5) * qhA;
    float n0 = (a0 + w7) * qbA;
    float n1 = (a1 + a0 + sk0 * w7) * aLo.x;
    float n2 = (a2 + a1) * qbA;
    float n3 = (a3 + a2 + sk1 * a1) * aLo.y;
    float n4 = (a4 + a3) * qbA;
    float n5 = (a5 + a4 + sk2 * a3) * aHi.x;
    float n6 = (a6 + a5) * qbA;
    float n7 = (a7 + a6 + sk3 * a5) * aHi.y;
    a0 = (n0 + hA) * qbB;
    a1 = (n1 + n0 + sk0 * hA) * bLo.x;
    a2 = (n2 + n1) * qbB;
    a3 = (n3 + n2 + sk1 * n1) * bLo.y;
    a4 = (n4 + n3) * qbB;
    a5 = (n5 + n4 + sk2 * n3) * bHi.x;
    a6 = (n6 + n5) * qbB;
    a7 = (n7 + n6 + sk3 * n5) * bHi.y;
    if (renorm) {  // every 8 steps, exact pow2
      float mx = fmaxf(fmaxf(fmaxf(a0, a1), fmaxf(a2, a3)),
                       fmaxf(fmaxf(a4, a5), fmaxf(a6, a7)));
      unsigned bits = __float_as_uint(mx);
      bool z = (bits == 0u);
      int e = (int)(bits >> 23) - 127;
      float f = __uint_as_float((254u - (bits >> 23)) << 23);  // 2^-e
      f = z ? 1.0f : f;
      a0 *= f; a1 *= f; a2 *= f; a3 *= f;
      a4 *= f; a5 *= f; a6 *= f; a7 *= f;
      E = z ? epd : (E + e);
    }
    s7d = dpp_shr1_f(a7);
    s6d = dpp_shr1_f(a6);
    s5d = dpp_shr1_f(a5);
    if (renorm) {
      epd = dpp_shr1_i(E);
      int de = epd - E;
      de = de < -126 ? -126 : (de > 60 ? 60 : de);
      corr = __int_as_float((de + 127) << 23);
      corr = (lane == 0) ? 0.0f : corr;
    }
  };

  const int R = (len - 1) >> 1;          // full pair-rounds
  const int leftover = (len - 1) & 1;
  const int PRtot = R + leftover;        // pairs touched
  const int NCg = (PRtot + CHP - 1) / CHP;
  const int cfull = R / CHP;

  {
    int need0 = 256 > Tc - 1 ? Tc - 1 : 256;
    wait_wm(need0);                      // steps 1..256 + blank region 0 ready
  }
  load_blank_region(0);
  if (NCg > 0) load_pairs(0, 0);
  __builtin_amdgcn_s_waitcnt(0x0f70);    // vmcnt(0): blanks0 + chunk0 landed
  if (NCg > 1) load_pairs(1, 1);

  uint4 raw[2];
  float2 blkp[2];
  if (NCg > 0) {  // entry prefetch: pairs 0,1 of chunk 0
    raw[0] = *(const uint4*)(&bufs[0][0 * PAIRB] + lane16);
    blkp[0] = *(const float2*)(blk_s + 0);
    raw[1] = *(const uint4*)(&bufs[0][1 * PAIRB] + lane16);
    blkp[1] = *(const float2*)(blk_s + 2);
  }

  for (int c = 0; c < cfull; ++c) {
    const char* base = &bufs[c & 1][0];
    const char* nbase = &bufs[(c + 1) & 1][0];
    const float* pb = blk_s + c * 32;
#pragma unroll
    for (int rr = 0; rr < 16; ++rr) {
      const int p = rr & 1;
      uint4 rw = raw[p];
      float2 bl = blkp[p];
      if (rr < 14) {  // prefetch 2 rounds ahead within chunk
        raw[p] = *(const uint4*)(base + (rr + 2) * PAIRB + lane16);
        blkp[p] = *(const float2*)(pb + (rr + 2) * 2);
      } else {        // cross-chunk prefetch (loads are ~13 rounds old)
        if (rr == 14) __builtin_amdgcn_s_waitcnt(0x0f70);  // vmcnt(0) only
        raw[p] = *(const uint4*)(nbase + (rr - 14) * PAIRB + lane16);
        blkp[p] = *(const float2*)(pb + 32 + (rr - 14) * 2);
      }
      round2(rw, bl, (rr & 3) == 3);
    }
    if (c + 2 < NCg) {  // refill the buffer just freed (vmcnt==0 here)
      if (((c + 2) & 7) == 0) {          // new 8-chunk group: gate + blanks
        const int r = (c + 2) >> 3;
        int need = 256 * (r + 1);
        if (need > Tc - 1) need = Tc - 1;
        wait_wm(need);
        load_blank_region(r);
      }
      load_pairs(c & 1, c + 2);
    }
  }

  // tail: remaining pair-rounds + optional single step, from tail chunk buffer
  __builtin_amdgcn_s_waitcnt(0x0f70);
  {
    const char* tb = &bufs[cfull & 1][0];
    const float* pbT = blk_s + cfull * 32;
    const int rem = R - cfull * CHP;
    for (int r = 0; r < rem; ++r) {
      uint4 rw = *(const uint4*)(tb + r * PAIRB + lane16);
      float2 bl = *(const float2*)(pbT + 2 * r);
      round2(rw, bl, (r & 3) == 3);
    }
    if (leftover) {  // final odd step: slot A of pair R
      uint4 rw = *(const uint4*)(tb + rem * PAIRB + lane16);
      float blA = *(pbT + 2 * rem);
      float2 flo = __half22float2(*(__half2*)&rw.x);
      float2 fhi = __half22float2(*(__half2*)&rw.y);
      float s7 = dpp_shr1_f(a7);
      int ep = dpp_shr1_i(E);
      int de = ep - E;
      de = de < -126 ? -126 : (de > 60 ? 60 : de);
      float c2 = __int_as_float((de + 127) << 23);
      c2 = (lane == 0) ? 0.0f : c2;
      float w7 = s7 * c2;
      float n0 = (a0 + w7) * blA;
      float n1 = (a1 + a0 + sk0 * w7) * flo.x;
      float n2 = (a2 + a1) * blA;
      float n3 = (a3 + a2 + sk1 * a1) * flo.y;
      float n4 = (a4 + a3) * blA;
      float n5 = (a5 + a4 + sk2 * a3) * fhi.x;
      float n6 = (a6 + a5) * blA;
      float n7 = (a7 + a6 + sk3 * a5) * fhi.y;
      a0 = n0; a1 = n1; a2 = n2; a3 = n3;
      a4 = n4; a5 = n5; a6 = n6; a7 = n7;
    }
  }

  // final combine: loss = -lse(alpha[2ll], alpha[2ll-1]) in log2 domain
  int sE = 2 * ll;
  int sP = sE - 1 < 0 ? 0 : sE - 1;
  int laneA = sE >> 3, jA = sE & 7;
  int laneB = sP >> 3, jB = sP & 7;
  float va = a0;
  if (jA == 1) va = a1;
  if (jA == 2) va = a2;
  if (jA == 3) va = a3;
  if (jA == 4) va = a4;
  if (jA == 5) va = a5;
  if (jA == 6) va = a6;
  if (jA == 7) va = a7;
  float vb = a0;
  if (jB == 1) vb = a1;
  if (jB == 2) vb = a2;
  if (jB == 3) vb = a3;
  if (jB == 4) vb = a4;
  if (jB == 5) vb = a5;
  if (jB == 6) vb = a6;
  if (jB == 7) vb = a7;
  float aA = __int_as_float(__builtin_amdgcn_ds_bpermute(laneA << 2, __float_as_int(va)));
  float aB = __int_as_float(__builtin_amdgcn_ds_bpermute(laneB << 2, __float_as_int(vb)));
  int EA = __builtin_amdgcn_ds_bpermute(laneA << 2, E);
  int EB = __builtin_amdgcn_ds_bpermute(laneB << 2, E);
  if (lane == 0) {
    float l1 = (aA > 0.0f) ? (float)EA + log2f(aA) : -1e30f;
    float l2 = (aB > 0.0f) ? (float)EB + log2f(aB) : -1e30f;
    float mm = fmaxf(l1, l2);
    float v = mm + log2f(exp2f(l1 - mm) + exp2f(l2 - mm));
    out[b] = -v * LN2F;
  }
}

}  // namespace

extern "C" void kernel_launch(void* const* d_in, const int* in_sizes, int n_in,
                              void* d_out, int out_size, void* d_ws, size_t ws_size,
                              hipStream_t stream) {
  const float* y = (const float*)d_in[0];   // [64,2000,128] f32
  const int* yt = (const int*)d_in[1];      // [64,200] i32
  const int* il = (const int*)d_in[2];      // [64] i32
  const int* lb = (const int*)d_in[3];      // [64] i32
  float* out = (float*)d_out;               // [64] f32
  char* W = (char*)d_ws;                    // 66,052,352 B incl. watermarks

  hipMemsetAsync(W + FLAGS_OFF, 0, Bc * sizeof(int), stream);  // clear flags
  hipLaunchKernelGGL(ctc_fused_kernel, dim3(2 * Bc), dim3(256), 0, stream,
                     y, W, yt, il, lb, out);
}

// Round 2
// 409.994 us; speedup vs baseline: 1.2146x; 1.2146x over previous
//
#include <hip/hip_runtime.h>
#include <hip/hip_fp16.h>

// CTC forward loss. B=64, T=2000, C=128 (blank=127), Lmax=200, S=401.
// SINGLE kernel, intra-block producer-consumer. One block per batch (256 thr):
//   wave 0      : alpha recursion (identical math to the proven 148us kernel:
//                 linear domain + pow2 exponent tracking, DPP halos, 8
//                 states/lane). Reads packed pairs from LDS double buffer.
//   waves 1..3  : producers. Per 16-pair chunk (32 time steps) they compute
//                 softmax + label-gather for rows t and ds_write the packed
//                 half2 pairs + f32 blanks directly into the LDS buffer the
//                 consumer will read next. No global W workspace at all
//                 (removes 66MB write + 33MB re-read of the 2-kernel version
//                 and the ~105us serialized pack pass).
// Sync: one __syncthreads() per chunk at a textually-uniform point; double
// buffer parity k&1. Producers fill chunk k+1 while wave 0 consumes chunk k.
// Codegen hazards from the failed fused attempt (VGPR 132->60, scratch
// spills) are avoided: consumer prefetch uses NAMED registers only (rawA/
// rawB), no runtime-indexed arrays, no global_load_lds/vmcnt in the consumer.

#define LOG2E 1.44269504088896340736f
#define LN2F  0.69314718055994530942f

namespace {

constexpr int Bc = 64, Tc = 2000, Cc = 128, Lmaxc = 200;
constexpr int PAIRB = 1024;                  // bytes per pair (64 lanes x 16)
constexpr int CHP = 16;                      // pairs per chunk (32 steps)
constexpr int CHB = CHP * PAIRB;             // 16 KB

__device__ __forceinline__ float dpp_shr1_f(float x) {  // lane i <- i-1, lane0 <- 0
  return __int_as_float(
      __builtin_amdgcn_update_dpp(0, __float_as_int(x), 0x138, 0xF, 0xF, true));
}
__device__ __forceinline__ int dpp_shr1_i(int x) {
  return __builtin_amdgcn_update_dpp(0, x, 0x138, 0xF, 0xF, true);
}
template <int CTRL>
__device__ __forceinline__ float dpp_add(float v) {
  return v + __int_as_float(
      __builtin_amdgcn_update_dpp(0, __float_as_int(v), CTRL, 0xF, 0xF, true));
}
__device__ __forceinline__ float wave_sum_bcast(float v) {  // full-wave sum
  v = dpp_add<0x111>(v);
  v = dpp_add<0x112>(v);
  v = dpp_add<0x114>(v);
  v = dpp_add<0x118>(v);
  v = dpp_add<0x142>(v);
  v = dpp_add<0x143>(v);
  return __int_as_float(__builtin_amdgcn_readlane(__float_as_int(v), 63));
}

__global__ __launch_bounds__(256) void ctc_fused_kernel(
    const float* __restrict__ y, const int* __restrict__ y_true,
    const int* __restrict__ in_len, const int* __restrict__ lab_len,
    float* __restrict__ out) {
  __shared__ __align__(16) char bufs[2][CHB];   // 32 KB pair double buffer
  __shared__ __align__(16) float blkb[2][32];   // blank probs per chunk

  const int b = blockIdx.x;
  const int wv = threadIdx.x >> 6, lane = threadIdx.x & 63;
  const int lane16 = lane * 16;

  int len = in_len[b];
  len = len < 1 ? 1 : (len > Tc ? Tc : len);
  const int R = (len - 1) >> 1;          // full pair-rounds
  const int leftover = (len - 1) & 1;
  const int PRtot = R + leftover;        // pairs touched
  const int NCg = (PRtot + CHP - 1) / CHP;
  const int cfull = R / CHP;
  const int* labs = y_true + b * Lmaxc;

  // ---- producer-side label classes (pack_kernel's fix() semantics) ----
  int pbase = 4 * lane;
  if (pbase > Lmaxc - 4) pbase = Lmaxc - 4;
  const int4 Lw = *(const int4*)(labs + pbase);
  auto fix = [&](int v, int idx) {
    int r = (idx > Lmaxc - 1) ? Lw.w : v;  // idx>199 -> labs[199]
    return r < 0 ? 0 : r;                  // padded -1 -> 0
  };
  const int c0 = fix(Lw.x, 4 * lane), c1 = fix(Lw.y, 4 * lane + 1);
  const int c2 = fix(Lw.z, 4 * lane + 2), c3 = fix(Lw.w, 4 * lane + 3);
  const float* yrow = y + (size_t)b * Tc * Cc + 2 * lane;

  // producer: rows t = 32*kp+wv, +3 within the chunk; packed pair + blank
  auto produce = [&](int kp) {
    char* pbuf = &bufs[kp & 1][0];
    float* bb = blkb[kp & 1];
    int thi = 32 * kp + 32;
    if (thi > Tc - 1) thi = Tc - 1;
#pragma unroll 4
    for (int t = 32 * kp + wv; t <= thi; t += 3) {
      const float2 yy = *(const float2*)(yrow + (size_t)t * Cc);
      float e0 = exp2f(fminf(yy.x * LOG2E, 50.f));
      float e1 = exp2f(fminf(yy.y * LOG2E, 50.f));
      const float rs = 1.0f / wave_sum_bcast(e0 + e1);
      unsigned q2 =
          __builtin_bit_cast(unsigned, __floats2half2_rn(e0 * rs, e1 * rs));
      unsigned g0 = (unsigned)__builtin_amdgcn_ds_bpermute((c0 >> 1) << 2, (int)q2);
      unsigned g1 = (unsigned)__builtin_amdgcn_ds_bpermute((c1 >> 1) << 2, (int)q2);
      unsigned g2 = (unsigned)__builtin_amdgcn_ds_bpermute((c2 >> 1) << 2, (int)q2);
      unsigned g3 = (unsigned)__builtin_amdgcn_ds_bpermute((c3 >> 1) << 2, (int)q2);
      unsigned h0 = (c0 & 1) ? (g0 >> 16) : (g0 & 0xFFFFu);
      unsigned h1 = (c1 & 1) ? (g1 >> 16) : (g1 & 0xFFFFu);
      unsigned h2 = (c2 & 1) ? (g2 >> 16) : (g2 & 0xFFFFu);
      unsigned h3 = (c3 & 1) ? (g3 >> 16) : (g3 & 0xFFFFu);
      const int pq = ((t - 1) >> 1) - CHP * kp, sl = 1 - (t & 1);
      *(uint2*)(pbuf + pq * PAIRB + lane16 + sl * 8) =
          make_uint2(h0 | (h1 << 16), h2 | (h3 << 16));
      if (lane == 63)  // blank = class 127 prob, f32
        bb[(t - 1) - 32 * kp] = e1 * rs;
    }
  };

  // ---- consumer-side per-lane state (wave 0 only uses it) ----
  const int ll = lab_len[b];
  auto labc = [&](int l) -> int {
    int lc = l < 0 ? 0 : (l > Lmaxc - 1 ? Lmaxc - 1 : l);
    int c = labs[lc];
    return c < 0 ? 0 : c;
  };
  const int c0i = labc(4 * lane), c1i = labc(4 * lane + 1);
  const int c2i = labc(4 * lane + 2), c3i = labc(4 * lane + 3);
  const int cm1 = labc(4 * lane - 1), cm2 = labc(4 * lane - 2);
  const float sk0 = (4 * lane >= 1 && c0i != cm1) ? 1.f : 0.f;
  const float sk1 = (c1i != c0i) ? 1.f : 0.f;
  const float sk2 = (c2i != c1i) ? 1.f : 0.f;
  const float sk3 = (c3i != c2i) ? 1.f : 0.f;
  const float skH = (lane >= 1 && cm1 != cm2) ? 1.f : 0.f;

  float a0 = 0.f, a1 = 0.f, a2 = 0.f, a3 = 0.f;
  float a4 = 0.f, a5 = 0.f, a6 = 0.f, a7 = 0.f;
  int E = 0;
  if (wv == 0) {  // seed from y row t=0 (row 0 is never packed)
    const float* y0 = y + (size_t)b * Tc * Cc + 2 * lane;
    float e0 = exp2f(fminf(y0[0] * LOG2E, 50.f));
    float e1 = exp2f(fminf(y0[1] * LOG2E, 50.f));
    const float rs = 1.0f / wave_sum_bcast(e0 + e1);
    int l0 = labs[0];
    l0 = l0 < 0 ? 0 : l0;
    float ev = (l0 & 1) ? e1 : e0;
    float q0 = __int_as_float(__builtin_amdgcn_readlane(__float_as_int(ev), l0 >> 1)) * rs;
    float qb = __int_as_float(__builtin_amdgcn_readlane(__float_as_int(e1), 63)) * rs;
    if (lane == 0) { a0 = qb; a1 = q0; }
  }
  float s7d = dpp_shr1_f(a7), s6d = dpp_shr1_f(a6), s5d = dpp_shr1_f(a5);
  int epd = 0;
  float corr = (lane == 0) ? 0.f : 1.f;

  // pair-round: 2 lattice steps from one 16B slot + f32 blank pair
  auto round2 = [&](uint4 rw, float2 bl, bool renorm) {
    float2 aLo = __half22float2(*(__half2*)&rw.x);
    float2 aHi = __half22float2(*(__half2*)&rw.y);
    float2 bLo = __half22float2(*(__half2*)&rw.z);
    float2 bHi = __half22float2(*(__half2*)&rw.w);
    const float qbA = bl.x, qbB = bl.y;
    const float qhA = dpp_shr1_f(aHi.y);  // halo label prob (VALU pipe)
    const float w7 = s7d * corr, w6 = s6d * corr, w5 = s5d * corr;
    const float hA = (w7 + w6 + skH * w5) * qhA;
    float n0 = (a0 + w7) * qbA;
    float n1 = (a1 + a0 + sk0 * w7) * aLo.x;
    float n2 = (a2 + a1) * qbA;
    float n3 = (a3 + a2 + sk1 * a1) * aLo.y;
    float n4 = (a4 + a3) * qbA;
    float n5 = (a5 + a4 + sk2 * a3) * aHi.x;
    float n6 = (a6 + a5) * qbA;
    float n7 = (a7 + a6 + sk3 * a5) * aHi.y;
    a0 = (n0 + hA) * qbB;
    a1 = (n1 + n0 + sk0 * hA) * bLo.x;
    a2 = (n2 + n1) * qbB;
    a3 = (n3 + n2 + sk1 * n1) * bLo.y;
    a4 = (n4 + n3) * qbB;
    a5 = (n5 + n4 + sk2 * n3) * bHi.x;
    a6 = (n6 + n5) * qbB;
    a7 = (n7 + n6 + sk3 * n5) * bHi.y;
    if (renorm) {  // every 8 steps, exact pow2
      float mx = fmaxf(fmaxf(fmaxf(a0, a1), fmaxf(a2, a3)),
                       fmaxf(fmaxf(a4, a5), fmaxf(a6, a7)));
      unsigned bits = __float_as_uint(mx);
      bool z = (bits == 0u);
      int e = (int)(bits >> 23) - 127;
      float f = __uint_as_float((254u - (bits >> 23)) << 23);  // 2^-e
      f = z ? 1.0f : f;
      a0 *= f; a1 *= f; a2 *= f; a3 *= f;
      a4 *= f; a5 *= f; a6 *= f; a7 *= f;
      E = z ? epd : (E + e);
    }
    s7d = dpp_shr1_f(a7);
    s6d = dpp_shr1_f(a6);
    s5d = dpp_shr1_f(a5);
    if (renorm) {
      epd = dpp_shr1_i(E);
      int de = epd - E;
      de = de < -126 ? -126 : (de > 60 ? 60 : de);
      corr = __int_as_float((de + 127) << 23);
      corr = (lane == 0) ? 0.0f : corr;
    }
  };

  // consume one full 16-round chunk. NAMED prefetch registers only.
  auto consume = [&](int k) {
    const char* cb = &bufs[k & 1][0];
    const float* pb = blkb[k & 1];
    uint4 rawA = *(const uint4*)(cb + 0 * PAIRB + lane16);
    float2 blA = *(const float2*)(pb + 0);
    uint4 rawB = *(const uint4*)(cb + 1 * PAIRB + lane16);
    float2 blB = *(const float2*)(pb + 2);
#pragma unroll
    for (int h = 0; h < 8; ++h) {
      uint4 ra = rawA;
      float2 ba = blA;
      if (h < 7) {
        rawA = *(const uint4*)(cb + (2 * h + 2) * PAIRB + lane16);
        blA = *(const float2*)(pb + (4 * h + 4));
      }
      round2(ra, ba, false);
      uint4 rb = rawB;
      float2 bb2 = blB;
      if (h < 7) {
        rawB = *(const uint4*)(cb + (2 * h + 3) * PAIRB + lane16);
        blB = *(const float2*)(pb + (4 * h + 6));
      }
      round2(rb, bb2, (h & 1) == 1);
    }
  };

  // ---- pipeline: uniform barriers, producers one chunk ahead ----
  if (wv != 0 && NCg > 0) produce(0);
  __syncthreads();
  for (int k = 0; k < cfull; ++k) {
    if (wv == 0) {
      consume(k);
    } else if (k + 1 < NCg) {
      produce(k + 1);
    }
    __syncthreads();
  }

  if (wv != 0) return;  // producers done (no barriers past this point)

  // tail: remaining pair-rounds + optional single step, from tail chunk
  {
    const char* tb = &bufs[cfull & 1][0];
    const float* pbT = blkb[cfull & 1];
    const int rem = R - cfull * CHP;
    for (int r = 0; r < rem; ++r) {
      uint4 rw = *(const uint4*)(tb + r * PAIRB + lane16);
      float2 bl = *(const float2*)(pbT + 2 * r);
      round2(rw, bl, (r & 3) == 3);
    }
    if (leftover) {  // final odd step: slot A of pair R
      uint4 rw = *(const uint4*)(tb + rem * PAIRB + lane16);
      float blA = *(pbT + 2 * rem);
      float2 flo = __half22float2(*(__half2*)&rw.x);
      float2 fhi = __half22float2(*(__half2*)&rw.y);
      float s7 = dpp_shr1_f(a7);
      int ep = dpp_shr1_i(E);
      int de = ep - E;
      de = de < -126 ? -126 : (de > 60 ? 60 : de);
      float c2v = __int_as_float((de + 127) << 23);
      c2v = (lane == 0) ? 0.0f : c2v;
      float w7 = s7 * c2v;
      float n0 = (a0 + w7) * blA;
      float n1 = (a1 + a0 + sk0 * w7) * flo.x;
      float n2 = (a2 + a1) * blA;
      float n3 = (a3 + a2 + sk1 * a1) * flo.y;
      float n4 = (a4 + a3) * blA;
      float n5 = (a5 + a4 + sk2 * a3) * fhi.x;
      float n6 = (a6 + a5) * blA;
      float n7 = (a7 + a6 + sk3 * a5) * fhi.y;
      a0 = n0; a1 = n1; a2 = n2; a3 = n3;
      a4 = n4; a5 = n5; a6 = n6; a7 = n7;
    }
  }

  // final combine: loss = -lse(alpha[2ll], alpha[2ll-1]) in log2 domain
  int sE = 2 * ll;
  int sP = sE - 1 < 0 ? 0 : sE - 1;
  int laneA = sE >> 3, jA = sE & 7;
  int laneB = sP >> 3, jB = sP & 7;
  float va = a0;
  if (jA == 1) va = a1;
  if (jA == 2) va = a2;
  if (jA == 3) va = a3;
  if (jA == 4) va = a4;
  if (jA == 5) va = a5;
  if (jA == 6) va = a6;
  if (jA == 7) va = a7;
  float vb = a0;
  if (jB == 1) vb = a1;
  if (jB == 2) vb = a2;
  if (jB == 3) vb = a3;
  if (jB == 4) vb = a4;
  if (jB == 5) vb = a5;
  if (jB == 6) vb = a6;
  if (jB == 7) vb = a7;
  float aA = __int_as_float(__builtin_amdgcn_ds_bpermute(laneA << 2, __float_as_int(va)));
  float aB = __int_as_float(__builtin_amdgcn_ds_bpermute(laneB << 2, __float_as_int(vb)));
  int EA = __builtin_amdgcn_ds_bpermute(laneA << 2, E);
  int EB = __builtin_amdgcn_ds_bpermute(laneB << 2, E);
  if (lane == 0) {
    float l1 = (aA > 0.0f) ? (float)EA + log2f(aA) : -1e30f;
    float l2 = (aB > 0.0f) ? (float)EB + log2f(aB) : -1e30f;
    float mm = fmaxf(l1, l2);
    float v = mm + log2f(exp2f(l1 - mm) + exp2f(l2 - mm));
    out[b] = -v * LN2F;
  }
}

}  // namespace

extern "C" void kernel_launch(void* const* d_in, const int* in_sizes, int n_in,
                              void* d_out, int out_size, void* d_ws, size_t ws_size,
                              hipStream_t stream) {
  const float* y = (const float*)d_in[0];   // [64,2000,128] f32
  const int* yt = (const int*)d_in[1];      // [64,200] i32
  const int* il = (const int*)d_in[2];      // [64] i32
  const int* lb = (const int*)d_in[3];      // [64] i32
  float* out = (float*)d_out;               // [64] f32
  (void)d_ws; (void)ws_size;                // no workspace needed anymore

  hipLaunchKernelGGL(ctc_fused_kernel, dim3(Bc), dim3(256), 0, stream,
                     y, yt, il, lb, out);
}

// Round 3
// 366.696 us; speedup vs baseline: 1.3580x; 1.1181x over previous
//
#include <hip/hip_runtime.h>
#include <hip/hip_fp16.h>

// CTC forward loss. B=64, T=2000, C=128 (blank=127), Lmax=200, S=401.
// SINGLE kernel, intra-block producer-consumer. One block per batch (256 thr):
//   wave 0      : alpha recursion (identical math to the proven 148us kernel:
//                 linear domain + pow2 exponent tracking, DPP halos, 8
//                 states/lane). Reads packed pairs from the LDS double buffer.
//   waves 1..3  : producers, PAIR-GRANULAR (v3): wave wv owns local pairs
//                 wv-1, wv-1+3, ... (<=6 pairs/chunk), fully unrolled with
//                 predication (compile-time trip count -> ~12 independent
//                 row chains in flight, issue-bound ~1us/chunk), and writes
//                 one contiguous ds_write_b128 per pair (16B/lane stride 16,
//                 conflict-free; v2's 8-way-conflicted b64 writes caused the
//                 1.17M SQ_LDS_BANK_CONFLICT and ~7us/chunk producer rate).
// Sync: one __syncthreads() per chunk at a textually-uniform point; double
// buffer parity k&1; producers fill chunk k+1 while wave 0 consumes chunk k.
// Per-(t,lane) math is op-identical to the passing v2 (same DPP-sum order,
// same 1.0f/x, same __floats2half2_rn, same bpermute gather) -> LDS contents
// bit-identical -> absmax must stay 0.0.

#define LOG2E 1.44269504088896340736f
#define LN2F  0.69314718055994530942f

namespace {

constexpr int Bc = 64, Tc = 2000, Cc = 128, Lmaxc = 200;
constexpr int PAIRB = 1024;                  // bytes per pair (64 lanes x 16)
constexpr int CHP = 16;                      // pairs per chunk (32 steps)
constexpr int CHB = CHP * PAIRB;             // 16 KB

__device__ __forceinline__ float dpp_shr1_f(float x) {  // lane i <- i-1, lane0 <- 0
  return __int_as_float(
      __builtin_amdgcn_update_dpp(0, __float_as_int(x), 0x138, 0xF, 0xF, true));
}
__device__ __forceinline__ int dpp_shr1_i(int x) {
  return __builtin_amdgcn_update_dpp(0, x, 0x138, 0xF, 0xF, true);
}
template <int CTRL>
__device__ __forceinline__ float dpp_add(float v) {
  return v + __int_as_float(
      __builtin_amdgcn_update_dpp(0, __float_as_int(v), CTRL, 0xF, 0xF, true));
}
__device__ __forceinline__ float wave_sum_bcast(float v) {  // full-wave sum
  v = dpp_add<0x111>(v);
  v = dpp_add<0x112>(v);
  v = dpp_add<0x114>(v);
  v = dpp_add<0x118>(v);
  v = dpp_add<0x142>(v);
  v = dpp_add<0x143>(v);
  return __int_as_float(__builtin_amdgcn_readlane(__float_as_int(v), 63));
}

__global__ __launch_bounds__(256, 1) void ctc_fused_kernel(
    const float* __restrict__ y, const int* __restrict__ y_true,
    const int* __restrict__ in_len, const int* __restrict__ lab_len,
    float* __restrict__ out) {
  __shared__ __align__(16) char bufs[2][CHB];   // 32 KB pair double buffer
  __shared__ __align__(16) float blkb[2][32];   // blank probs per chunk

  const int b = blockIdx.x;
  const int wv = threadIdx.x >> 6, lane = threadIdx.x & 63;
  const int lane16 = lane * 16;

  int len = in_len[b];
  len = len < 1 ? 1 : (len > Tc ? Tc : len);
  const int R = (len - 1) >> 1;          // full pair-rounds
  const int leftover = (len - 1) & 1;
  const int PRtot = R + leftover;        // pairs touched
  const int NCg = (PRtot + CHP - 1) / CHP;
  const int cfull = R / CHP;
  const int* labs = y_true + b * Lmaxc;

  // ---- producer-side label classes (pack_kernel's fix() semantics) ----
  int pbase = 4 * lane;
  if (pbase > Lmaxc - 4) pbase = Lmaxc - 4;
  const int4 Lw = *(const int4*)(labs + pbase);
  auto fix = [&](int v, int idx) {
    int r = (idx > Lmaxc - 1) ? Lw.w : v;  // idx>199 -> labs[199]
    return r < 0 ? 0 : r;                  // padded -1 -> 0
  };
  const int c0 = fix(Lw.x, 4 * lane), c1 = fix(Lw.y, 4 * lane + 1);
  const int c2 = fix(Lw.z, 4 * lane + 2), c3 = fix(Lw.w, 4 * lane + 3);
  const float* yrow = y + (size_t)b * Tc * Cc + 2 * lane;

  // one softmax+gather row -> packed 8B (4 half label probs); bl = blank prob
  auto pack_row = [&](int t, float& bl) -> uint2 {
    const float2 yy = *(const float2*)(yrow + (size_t)t * Cc);
    float e0 = exp2f(fminf(yy.x * LOG2E, 50.f));
    float e1 = exp2f(fminf(yy.y * LOG2E, 50.f));
    const float rs = 1.0f / wave_sum_bcast(e0 + e1);
    unsigned q2 =
        __builtin_bit_cast(unsigned, __floats2half2_rn(e0 * rs, e1 * rs));
    unsigned g0 = (unsigned)__builtin_amdgcn_ds_bpermute((c0 >> 1) << 2, (int)q2);
    unsigned g1 = (unsigned)__builtin_amdgcn_ds_bpermute((c1 >> 1) << 2, (int)q2);
    unsigned g2 = (unsigned)__builtin_amdgcn_ds_bpermute((c2 >> 1) << 2, (int)q2);
    unsigned g3 = (unsigned)__builtin_amdgcn_ds_bpermute((c3 >> 1) << 2, (int)q2);
    unsigned h0 = (c0 & 1) ? (g0 >> 16) : (g0 & 0xFFFFu);
    unsigned h1 = (c1 & 1) ? (g1 >> 16) : (g1 & 0xFFFFu);
    unsigned h2 = (c2 & 1) ? (g2 >> 16) : (g2 & 0xFFFFu);
    unsigned h3 = (c3 & 1) ? (g3 >> 16) : (g3 & 0xFFFFu);
    bl = e1 * rs;  // lane 63 holds class-127 (blank) prob
    return make_uint2(h0 | (h1 << 16), h2 | (h3 << 16));
  };

  // producer: wave wv packs local pairs wv-1, wv-1+3, ... of chunk kp.
  // Fully unrolled (compile-time bound 6) with predication for ILP.
  auto produce = [&](int kp) {
    char* pbuf = &bufs[kp & 1][0];
    float* bb = blkb[kp & 1];
#pragma unroll
    for (int i = 0; i < 6; ++i) {
      const int pq = (wv - 1) + 3 * i;       // local pair in [0,16)
      const int gp = CHP * kp + pq;          // global pair
      const int t1 = 2 * gp + 1;             // slot A step (odd)
      if (pq < CHP && t1 <= Tc - 1) {
        int t2 = t1 + 1;                     // slot B step (even)
        if (t2 > Tc - 1) t2 = Tc - 1;        // clamp: garbage B, never read
        float blA, blB;
        const uint2 wA = pack_row(t1, blA);
        const uint2 wB = pack_row(t2, blB);
        *(uint4*)(pbuf + pq * PAIRB + lane16) =
            make_uint4(wA.x, wA.y, wB.x, wB.y);   // b128, conflict-free
        if (lane == 63)
          *(float2*)(bb + 2 * pq) = make_float2(blA, blB);
      }
    }
  };

  // ---- consumer-side per-lane state (wave 0 only uses it) ----
  const int ll = lab_len[b];
  auto labc = [&](int l) -> int {
    int lc = l < 0 ? 0 : (l > Lmaxc - 1 ? Lmaxc - 1 : l);
    int c = labs[lc];
    return c < 0 ? 0 : c;
  };
  const int c0i = labc(4 * lane), c1i = labc(4 * lane + 1);
  const int c2i = labc(4 * lane + 2), c3i = labc(4 * lane + 3);
  const int cm1 = labc(4 * lane - 1), cm2 = labc(4 * lane - 2);
  const float sk0 = (4 * lane >= 1 && c0i != cm1) ? 1.f : 0.f;
  const float sk1 = (c1i != c0i) ? 1.f : 0.f;
  const float sk2 = (c2i != c1i) ? 1.f : 0.f;
  const float sk3 = (c3i != c2i) ? 1.f : 0.f;
  const float skH = (lane >= 1 && cm1 != cm2) ? 1.f : 0.f;

  float a0 = 0.f, a1 = 0.f, a2 = 0.f, a3 = 0.f;
  float a4 = 0.f, a5 = 0.f, a6 = 0.f, a7 = 0.f;
  int E = 0;
  if (wv == 0) {  // seed from y row t=0 (row 0 is never packed)
    const float* y0 = y + (size_t)b * Tc * Cc + 2 * lane;
    float e0 = exp2f(fminf(y0[0] * LOG2E, 50.f));
    float e1 = exp2f(fminf(y0[1] * LOG2E, 50.f));
    const float rs = 1.0f / wave_sum_bcast(e0 + e1);
    int l0 = labs[0];
    l0 = l0 < 0 ? 0 : l0;
    float ev = (l0 & 1) ? e1 : e0;
    float q0 = __int_as_float(__builtin_amdgcn_readlane(__float_as_int(ev), l0 >> 1)) * rs;
    float qb = __int_as_float(__builtin_amdgcn_readlane(__float_as_int(e1), 63)) * rs;
    if (lane == 0) { a0 = qb; a1 = q0; }
  }
  float s7d = dpp_shr1_f(a7), s6d = dpp_shr1_f(a6), s5d = dpp_shr1_f(a5);
  int epd = 0;
  float corr = (lane == 0) ? 0.f : 1.f;

  // pair-round: 2 lattice steps from one 16B slot + f32 blank pair
  auto round2 = [&](uint4 rw, float2 bl, bool renorm) {
    float2 aLo = __half22float2(*(__half2*)&rw.x);
    float2 aHi = __half22float2(*(__half2*)&rw.y);
    float2 bLo = __half22float2(*(__half2*)&rw.z);
    float2 bHi = __half22float2(*(__half2*)&rw.w);
    const float qbA = bl.x, qbB = bl.y;
    const float qhA = dpp_shr1_f(aHi.y);  // halo label prob (VALU pipe)
    const float w7 = s7d * corr, w6 = s6d * corr, w5 = s5d * corr;
    const float hA = (w7 + w6 + skH * w5) * qhA;
    float n0 = (a0 + w7) * qbA;
    float n1 = (a1 + a0 + sk0 * w7) * aLo.x;
    float n2 = (a2 + a1) * qbA;
    float n3 = (a3 + a2 + sk1 * a1) * aLo.y;
    float n4 = (a4 + a3) * qbA;
    float n5 = (a5 + a4 + sk2 * a3) * aHi.x;
    float n6 = (a6 + a5) * qbA;
    float n7 = (a7 + a6 + sk3 * a5) * aHi.y;
    a0 = (n0 + hA) * qbB;
    a1 = (n1 + n0 + sk0 * hA) * bLo.x;
    a2 = (n2 + n1) * qbB;
    a3 = (n3 + n2 + sk1 * n1) * bLo.y;
    a4 = (n4 + n3) * qbB;
    a5 = (n5 + n4 + sk2 * n3) * bHi.x;
    a6 = (n6 + n5) * qbB;
    a7 = (n7 + n6 + sk3 * n5) * bHi.y;
    if (renorm) {  // every 8 steps, exact pow2
      float mx = fmaxf(fmaxf(fmaxf(a0, a1), fmaxf(a2, a3)),
                       fmaxf(fmaxf(a4, a5), fmaxf(a6, a7)));
      unsigned bits = __float_as_uint(mx);
      bool z = (bits == 0u);
      int e = (int)(bits >> 23) - 127;
      float f = __uint_as_float((254u - (bits >> 23)) << 23);  // 2^-e
      f = z ? 1.0f : f;
      a0 *= f; a1 *= f; a2 *= f; a3 *= f;
      a4 *= f; a5 *= f; a6 *= f; a7 *= f;
      E = z ? epd : (E + e);
    }
    s7d = dpp_shr1_f(a7);
    s6d = dpp_shr1_f(a6);
    s5d = dpp_shr1_f(a5);
    if (renorm) {
      epd = dpp_shr1_i(E);
      int de = epd - E;
      de = de < -126 ? -126 : (de > 60 ? 60 : de);
      corr = __int_as_float((de + 127) << 23);
      corr = (lane == 0) ? 0.0f : corr;
    }
  };

  // consume one full 16-round chunk. NAMED prefetch registers only.
  auto consume = [&](int k) {
    const char* cb = &bufs[k & 1][0];
    const float* pb = blkb[k & 1];
    uint4 rawA = *(const uint4*)(cb + 0 * PAIRB + lane16);
    float2 blA = *(const float2*)(pb + 0);
    uint4 rawB = *(const uint4*)(cb + 1 * PAIRB + lane16);
    float2 blB = *(const float2*)(pb + 2);
#pragma unroll
    for (int h = 0; h < 8; ++h) {
      uint4 ra = rawA;
      float2 ba = blA;
      if (h < 7) {
        rawA = *(const uint4*)(cb + (2 * h + 2) * PAIRB + lane16);
        blA = *(const float2*)(pb + (4 * h + 4));
      }
      round2(ra, ba, false);
      uint4 rb = rawB;
      float2 bb2 = blB;
      if (h < 7) {
        rawB = *(const uint4*)(cb + (2 * h + 3) * PAIRB + lane16);
        blB = *(const float2*)(pb + (4 * h + 6));
      }
      round2(rb, bb2, (h & 1) == 1);
    }
  };

  // ---- pipeline: uniform barriers, producers one chunk ahead ----
  if (wv != 0 && NCg > 0) produce(0);
  __syncthreads();
  for (int k = 0; k < cfull; ++k) {
    if (wv == 0) {
      consume(k);
    } else if (k + 1 < NCg) {
      produce(k + 1);
    }
    __syncthreads();
  }

  if (wv != 0) return;  // producers done (no barriers past this point)

  // tail: remaining pair-rounds + optional single step, from tail chunk
  {
    const char* tb = &bufs[cfull & 1][0];
    const float* pbT = blkb[cfull & 1];
    const int rem = R - cfull * CHP;
    for (int r = 0; r < rem; ++r) {
      uint4 rw = *(const uint4*)(tb + r * PAIRB + lane16);
      float2 bl = *(const float2*)(pbT + 2 * r);
      round2(rw, bl, (r & 3) == 3);
    }
    if (leftover) {  // final odd step: slot A of pair R
      uint4 rw = *(const uint4*)(tb + rem * PAIRB + lane16);
      float blA = *(pbT + 2 * rem);
      float2 flo = __half22float2(*(__half2*)&rw.x);
      float2 fhi = __half22float2(*(__half2*)&rw.y);
      float s7 = dpp_shr1_f(a7);
      int ep = dpp_shr1_i(E);
      int de = ep - E;
      de = de < -126 ? -126 : (de > 60 ? 60 : de);
      float c2v = __int_as_float((de + 127) << 23);
      c2v = (lane == 0) ? 0.0f : c2v;
      float w7 = s7 * c2v;
      float n0 = (a0 + w7) * blA;
      float n1 = (a1 + a0 + sk0 * w7) * flo.x;
      float n2 = (a2 + a1) * blA;
      float n3 = (a3 + a2 + sk1 * a1) * flo.y;
      float n4 = (a4 + a3) * blA;
      float n5 = (a5 + a4 + sk2 * a3) * fhi.x;
      float n6 = (a6 + a5) * blA;
      float n7 = (a7 + a6 + sk3 * a5) * fhi.y;
      a0 = n0; a1 = n1; a2 = n2; a3 = n3;
      a4 = n4; a5 = n5; a6 = n6; a7 = n7;
    }
  }

  // final combine: loss = -lse(alpha[2ll], alpha[2ll-1]) in log2 domain
  int sE = 2 * ll;
  int sP = sE - 1 < 0 ? 0 : sE - 1;
  int laneA = sE >> 3, jA = sE & 7;
  int laneB = sP >> 3, jB = sP & 7;
  float va = a0;
  if (jA == 1) va = a1;
  if (jA == 2) va = a2;
  if (jA == 3) va = a3;
  if (jA == 4) va = a4;
  if (jA == 5) va = a5;
  if (jA == 6) va = a6;
  if (jA == 7) va = a7;
  float vb = a0;
  if (jB == 1) vb = a1;
  if (jB == 2) vb = a2;
  if (jB == 3) vb = a3;
  if (jB == 4) vb = a4;
  if (jB == 5) vb = a5;
  if (jB == 6) vb = a6;
  if (jB == 7) vb = a7;
  float aA = __int_as_float(__builtin_amdgcn_ds_bpermute(laneA << 2, __float_as_int(va)));
  float aB = __int_as_float(__builtin_amdgcn_ds_bpermute(laneB << 2, __float_as_int(vb)));
  int EA = __builtin_amdgcn_ds_bpermute(laneA << 2, E);
  int EB = __builtin_amdgcn_ds_bpermute(laneB << 2, E);
  if (lane == 0) {
    float l1 = (aA > 0.0f) ? (float)EA + log2f(aA) : -1e30f;
    float l2 = (aB > 0.0f) ? (float)EB + log2f(aB) : -1e30f;
    float mm = fmaxf(l1, l2);
    float v = mm + log2f(exp2f(l1 - mm) + exp2f(l2 - mm));
    out[b] = -v * LN2F;
  }
}

}  // namespace

extern "C" void kernel_launch(void* const* d_in, const int* in_sizes, int n_in,
                              void* d_out, int out_size, void* d_ws, size_t ws_size,
                              hipStream_t stream) {
  const float* y = (const float*)d_in[0];   // [64,2000,128] f32
  const int* yt = (const int*)d_in[1];      // [64,200] i32
  const int* il = (const int*)d_in[2];      // [64] i32
  const int* lb = (const int*)d_in[3];      // [64] i32
  float* out = (float*)d_out;               // [64] f32
  (void)d_ws; (void)ws_size;                // no workspace needed

  hipLaunchKernelGGL(ctc_fused_kernel, dim3(Bc), dim3(256), 0, stream,
                     y, yt, il, lb, out);
}

// Round 4
// 226.299 us; speedup vs baseline: 2.2006x; 1.6204x over previous
//
#include <hip/hip_runtime.h>
#include <hip/hip_fp16.h>

// CTC forward loss. B=64, T=2000, C=128 (blank=127), Lmax=200, S=401.
// SINGLE kernel, intra-block producer-consumer. One block per batch (256 thr):
//   wave 0      : alpha recursion (identical math to the proven 148us kernel:
//                 linear domain + pow2 exponent tracking, DPP halos, 8
//                 states/lane). Reads packed pairs from the LDS double buffer.
//   waves 1..3  : producers, pair-granular, BRANCH-FREE (v4): wave wv owns
//                 local pairs wv-1, wv-1+3i (i<6). v3's wave-uniform
//                 predicates emitted scalar branches -> 6 basic blocks -> no
//                 cross-pair scheduling -> each pair serially ate ~900cyc of
//                 cold HBM load latency (VGPR stayed 68; 4.6us/chunk vs the
//                 consumer's 2.4). v4 clamps t instead of predicating, writes
//                 garbage pairs to scratch LDS slots (buffer holds 18 pairs;
//                 consumer provably reads only slots 0..15 and pairs < R),
//                 and splits produce() into stage 1 (12 row loads -> NAMED
//                 registers, all in flight) + stage 2 (6 pair computes,
//                 straight-line) so the latency is paid once per chunk.
// Sync: one __syncthreads() per chunk at a textually-uniform point; double
// buffer parity k&1; producers fill chunk k+1 while wave 0 consumes chunk k.
// Valid-pair math is op-identical to the passing v3 -> absmax must stay 0.0.

#define LOG2E 1.44269504088896340736f
#define LN2F  0.69314718055994530942f

namespace {

constexpr int Bc = 64, Tc = 2000, Cc = 128, Lmaxc = 200;
constexpr int PAIRB = 1024;                  // bytes per pair (64 lanes x 16)
constexpr int CHP = 16;                      // pairs per chunk (32 steps)
constexpr int CHPA = 18;                     // allocated pair slots (2 scratch)
constexpr int CHB = CHPA * PAIRB;            // 18 KB per buffer

__device__ __forceinline__ float dpp_shr1_f(float x) {  // lane i <- i-1, lane0 <- 0
  return __int_as_float(
      __builtin_amdgcn_update_dpp(0, __float_as_int(x), 0x138, 0xF, 0xF, true));
}
__device__ __forceinline__ int dpp_shr1_i(int x) {
  return __builtin_amdgcn_update_dpp(0, x, 0x138, 0xF, 0xF, true);
}
template <int CTRL>
__device__ __forceinline__ float dpp_add(float v) {
  return v + __int_as_float(
      __builtin_amdgcn_update_dpp(0, __float_as_int(v), CTRL, 0xF, 0xF, true));
}
__device__ __forceinline__ float wave_sum_bcast(float v) {  // full-wave sum
  v = dpp_add<0x111>(v);
  v = dpp_add<0x112>(v);
  v = dpp_add<0x114>(v);
  v = dpp_add<0x118>(v);
  v = dpp_add<0x142>(v);
  v = dpp_add<0x143>(v);
  return __int_as_float(__builtin_amdgcn_readlane(__float_as_int(v), 63));
}

__global__ __launch_bounds__(256, 1) void ctc_fused_kernel(
    const float* __restrict__ y, const int* __restrict__ y_true,
    const int* __restrict__ in_len, const int* __restrict__ lab_len,
    float* __restrict__ out) {
  __shared__ __align__(16) char bufs[2][CHB];   // 36 KB pair double buffer
  __shared__ __align__(16) float blkb[2][40];   // blank probs (+scratch tail)

  const int b = blockIdx.x;
  const int wv = threadIdx.x >> 6, lane = threadIdx.x & 63;
  const int lane16 = lane * 16;

  int len = in_len[b];
  len = len < 1 ? 1 : (len > Tc ? Tc : len);
  const int R = (len - 1) >> 1;          // full pair-rounds
  const int leftover = (len - 1) & 1;
  const int PRtot = R + leftover;        // pairs touched
  const int NCg = (PRtot + CHP - 1) / CHP;
  const int cfull = R / CHP;
  const int* labs = y_true + b * Lmaxc;

  // ---- producer-side label classes (pack_kernel's fix() semantics) ----
  int pbase = 4 * lane;
  if (pbase > Lmaxc - 4) pbase = Lmaxc - 4;
  const int4 Lw = *(const int4*)(labs + pbase);
  auto fix = [&](int v, int idx) {
    int r = (idx > Lmaxc - 1) ? Lw.w : v;  // idx>199 -> labs[199]
    return r < 0 ? 0 : r;                  // padded -1 -> 0
  };
  const int c0 = fix(Lw.x, 4 * lane), c1 = fix(Lw.y, 4 * lane + 1);
  const int c2 = fix(Lw.z, 4 * lane + 2), c3 = fix(Lw.w, 4 * lane + 3);
  const float* yrow = y + (size_t)b * Tc * Cc + 2 * lane;

  // softmax+gather from a pre-loaded row -> packed 8B; bl = blank prob
  auto pack2 = [&](float2 yy, float& bl) -> uint2 {
    float e0 = exp2f(fminf(yy.x * LOG2E, 50.f));
    float e1 = exp2f(fminf(yy.y * LOG2E, 50.f));
    const float rs = 1.0f / wave_sum_bcast(e0 + e1);
    unsigned q2 =
        __builtin_bit_cast(unsigned, __floats2half2_rn(e0 * rs, e1 * rs));
    unsigned g0 = (unsigned)__builtin_amdgcn_ds_bpermute((c0 >> 1) << 2, (int)q2);
    unsigned g1 = (unsigned)__builtin_amdgcn_ds_bpermute((c1 >> 1) << 2, (int)q2);
    unsigned g2 = (unsigned)__builtin_amdgcn_ds_bpermute((c2 >> 1) << 2, (int)q2);
    unsigned g3 = (unsigned)__builtin_amdgcn_ds_bpermute((c3 >> 1) << 2, (int)q2);
    unsigned h0 = (c0 & 1) ? (g0 >> 16) : (g0 & 0xFFFFu);
    unsigned h1 = (c1 & 1) ? (g1 >> 16) : (g1 & 0xFFFFu);
    unsigned h2 = (c2 & 1) ? (g2 >> 16) : (g2 & 0xFFFFu);
    unsigned h3 = (c3 & 1) ? (g3 >> 16) : (g3 & 0xFFFFu);
    bl = e1 * rs;  // lane 63 holds class-127 (blank) prob
    return make_uint2(h0 | (h1 << 16), h2 | (h3 << 16));
  };

  // producer: wave wv packs local pairs wv-1 + 3i (i<6) of chunk kp.
  // Branch-free: t clamped; garbage pairs land in scratch slots 16/17 or at
  // clamped rows -- never read by the consumer (reads slots 0..15, pairs < R).
  auto produce = [&](int kp) {
    char* pbuf = &bufs[kp & 1][0];
    float* bb = blkb[kp & 1];
    const int pq0 = wv - 1;              // 0,1,2
    const int tbase = 32 * kp + 1;       // step of slot A of local pair 0
    // ---- stage 1: all 12 row loads in flight (named regs only) ----
    float2 yA0, yB0, yA1, yB1, yA2, yB2, yA3, yB3, yA4, yB4, yA5, yB5;
#define LOADP(i, yA, yB)                                    \
  {                                                         \
    int tA = tbase + 2 * (pq0 + 3 * (i));                   \
    int tB = tA + 1;                                        \
    tA = tA > Tc - 1 ? Tc - 1 : tA;                         \
    tB = tB > Tc - 1 ? Tc - 1 : tB;                         \
    yA = *(const float2*)(yrow + (size_t)tA * Cc);          \
    yB = *(const float2*)(yrow + (size_t)tB * Cc);          \
  }
    LOADP(0, yA0, yB0)
    LOADP(1, yA1, yB1)
    LOADP(2, yA2, yB2)
    LOADP(3, yA3, yB3)
    LOADP(4, yA4, yB4)
    LOADP(5, yA5, yB5)
#undef LOADP
    // ---- stage 2: compute + write 6 pairs, straight-line ----
#define PACKP(i, yA, yB)                                            \
  {                                                                 \
    const int pq = pq0 + 3 * (i);                                   \
    float blA, blB;                                                 \
    const uint2 wA = pack2(yA, blA);                                \
    const uint2 wB = pack2(yB, blB);                                \
    *(uint4*)(pbuf + pq * PAIRB + lane16) =                         \
        make_uint4(wA.x, wA.y, wB.x, wB.y);                         \
    if (lane == 63) *(float2*)(bb + 2 * pq) = make_float2(blA, blB); \
  }
    PACKP(0, yA0, yB0)
    PACKP(1, yA1, yB1)
    PACKP(2, yA2, yB2)
    PACKP(3, yA3, yB3)
    PACKP(4, yA4, yB4)
    PACKP(5, yA5, yB5)
#undef PACKP
  };

  // ---- consumer-side per-lane state (wave 0 only uses it) ----
  const int ll = lab_len[b];
  auto labc = [&](int l) -> int {
    int lc = l < 0 ? 0 : (l > Lmaxc - 1 ? Lmaxc - 1 : l);
    int c = labs[lc];
    return c < 0 ? 0 : c;
  };
  const int c0i = labc(4 * lane), c1i = labc(4 * lane + 1);
  const int c2i = labc(4 * lane + 2), c3i = labc(4 * lane + 3);
  const int cm1 = labc(4 * lane - 1), cm2 = labc(4 * lane - 2);
  const float sk0 = (4 * lane >= 1 && c0i != cm1) ? 1.f : 0.f;
  const float sk1 = (c1i != c0i) ? 1.f : 0.f;
  const float sk2 = (c2i != c1i) ? 1.f : 0.f;
  const float sk3 = (c3i != c2i) ? 1.f : 0.f;
  const float skH = (lane >= 1 && cm1 != cm2) ? 1.f : 0.f;

  float a0 = 0.f, a1 = 0.f, a2 = 0.f, a3 = 0.f;
  float a4 = 0.f, a5 = 0.f, a6 = 0.f, a7 = 0.f;
  int E = 0;
  if (wv == 0) {  // seed from y row t=0 (row 0 is never packed)
    const float* y0 = y + (size_t)b * Tc * Cc + 2 * lane;
    float e0 = exp2f(fminf(y0[0] * LOG2E, 50.f));
    float e1 = exp2f(fminf(y0[1] * LOG2E, 50.f));
    const float rs = 1.0f / wave_sum_bcast(e0 + e1);
    int l0 = labs[0];
    l0 = l0 < 0 ? 0 : l0;
    float ev = (l0 & 1) ? e1 : e0;
    float q0 = __int_as_float(__builtin_amdgcn_readlane(__float_as_int(ev), l0 >> 1)) * rs;
    float qb = __int_as_float(__builtin_amdgcn_readlane(__float_as_int(e1), 63)) * rs;
    if (lane == 0) { a0 = qb; a1 = q0; }
  }
  float s7d = dpp_shr1_f(a7), s6d = dpp_shr1_f(a6), s5d = dpp_shr1_f(a5);
  int epd = 0;
  float corr = (lane == 0) ? 0.f : 1.f;

  // pair-round: 2 lattice steps from one 16B slot + f32 blank pair
  auto round2 = [&](uint4 rw, float2 bl, bool renorm) {
    float2 aLo = __half22float2(*(__half2*)&rw.x);
    float2 aHi = __half22float2(*(__half2*)&rw.y);
    float2 bLo = __half22float2(*(__half2*)&rw.z);
    float2 bHi = __half22float2(*(__half2*)&rw.w);
    const float qbA = bl.x, qbB = bl.y;
    const float qhA = dpp_shr1_f(aHi.y);  // halo label prob (VALU pipe)
    const float w7 = s7d * corr, w6 = s6d * corr, w5 = s5d * corr;
    const float hA = (w7 + w6 + skH * w5) * qhA;
    float n0 = (a0 + w7) * qbA;
    float n1 = (a1 + a0 + sk0 * w7) * aLo.x;
    float n2 = (a2 + a1) * qbA;
    float n3 = (a3 + a2 + sk1 * a1) * aLo.y;
    float n4 = (a4 + a3) * qbA;
    float n5 = (a5 + a4 + sk2 * a3) * aHi.x;
    float n6 = (a6 + a5) * qbA;
    float n7 = (a7 + a6 + sk3 * a5) * aHi.y;
    a0 = (n0 + hA) * qbB;
    a1 = (n1 + n0 + sk0 * hA) * bLo.x;
    a2 = (n2 + n1) * qbB;
    a3 = (n3 + n2 + sk1 * n1) * bLo.y;
    a4 = (n4 + n3) * qbB;
    a5 = (n5 + n4 + sk2 * n3) * bHi.x;
    a6 = (n6 + n5) * qbB;
    a7 = (n7 + n6 + sk3 * n5) * bHi.y;
    if (renorm) {  // every 8 steps, exact pow2
      float mx = fmaxf(fmaxf(fmaxf(a0, a1), fmaxf(a2, a3)),
                       fmaxf(fmaxf(a4, a5), fmaxf(a6, a7)));
      unsigned bits = __float_as_uint(mx);
      bool z = (bits == 0u);
      int e = (int)(bits >> 23) - 127;
      float f = __uint_as_float((254u - (bits >> 23)) << 23);  // 2^-e
      f = z ? 1.0f : f;
      a0 *= f; a1 *= f; a2 *= f; a3 *= f;
      a4 *= f; a5 *= f; a6 *= f; a7 *= f;
      E = z ? epd : (E + e);
    }
    s7d = dpp_shr1_f(a7);
    s6d = dpp_shr1_f(a6);
    s5d = dpp_shr1_f(a5);
    if (renorm) {
      epd = dpp_shr1_i(E);
      int de = epd - E;
      de = de < -126 ? -126 : (de > 60 ? 60 : de);
      corr = __int_as_float((de + 127) << 23);
      corr = (lane == 0) ? 0.0f : corr;
    }
  };

  // consume one full 16-round chunk. NAMED prefetch registers only.
  auto consume = [&](int k) {
    const char* cb = &bufs[k & 1][0];
    const float* pb = blkb[k & 1];
    uint4 rawA = *(const uint4*)(cb + 0 * PAIRB + lane16);
    float2 blA = *(const float2*)(pb + 0);
    uint4 rawB = *(const uint4*)(cb + 1 * PAIRB + lane16);
    float2 blB = *(const float2*)(pb + 2);
#pragma unroll
    for (int h = 0; h < 8; ++h) {
      uint4 ra = rawA;
      float2 ba = blA;
      if (h < 7) {
        rawA = *(const uint4*)(cb + (2 * h + 2) * PAIRB + lane16);
        blA = *(const float2*)(pb + (4 * h + 4));
      }
      round2(ra, ba, false);
      uint4 rb = rawB;
      float2 bb2 = blB;
      if (h < 7) {
        rawB = *(const uint4*)(cb + (2 * h + 3) * PAIRB + lane16);
        blB = *(const float2*)(pb + (4 * h + 6));
      }
      round2(rb, bb2, (h & 1) == 1);
    }
  };

  // ---- pipeline: uniform barriers, producers one chunk ahead ----
  if (wv != 0 && NCg > 0) produce(0);
  __syncthreads();
  for (int k = 0; k < cfull; ++k) {
    if (wv == 0) {
      consume(k);
    } else if (k + 1 < NCg) {
      produce(k + 1);
    }
    __syncthreads();
  }

  if (wv != 0) return;  // producers done (no barriers past this point)

  // tail: remaining pair-rounds + optional single step, from tail chunk
  {
    const char* tb = &bufs[cfull & 1][0];
    const float* pbT = blkb[cfull & 1];
    const int rem = R - cfull * CHP;
    for (int r = 0; r < rem; ++r) {
      uint4 rw = *(const uint4*)(tb + r * PAIRB + lane16);
      float2 bl = *(const float2*)(pbT + 2 * r);
      round2(rw, bl, (r & 3) == 3);
    }
    if (leftover) {  // final odd step: slot A of pair R
      uint4 rw = *(const uint4*)(tb + rem * PAIRB + lane16);
      float blA = *(pbT + 2 * rem);
      float2 flo = __half22float2(*(__half2*)&rw.x);
      float2 fhi = __half22float2(*(__half2*)&rw.y);
      float s7 = dpp_shr1_f(a7);
      int ep = dpp_shr1_i(E);
      int de = ep - E;
      de = de < -126 ? -126 : (de > 60 ? 60 : de);
      float c2v = __int_as_float((de + 127) << 23);
      c2v = (lane == 0) ? 0.0f : c2v;
      float w7 = s7 * c2v;
      float n0 = (a0 + w7) * blA;
      float n1 = (a1 + a0 + sk0 * w7) * flo.x;
      float n2 = (a2 + a1) * blA;
      float n3 = (a3 + a2 + sk1 * a1) * flo.y;
      float n4 = (a4 + a3) * blA;
      float n5 = (a5 + a4 + sk2 * a3) * fhi.x;
      float n6 = (a6 + a5) * blA;
      float n7 = (a7 + a6 + sk3 * a5) * fhi.y;
      a0 = n0; a1 = n1; a2 = n2; a3 = n3;
      a4 = n4; a5 = n5; a6 = n6; a7 = n7;
    }
  }

  // final combine: loss = -lse(alpha[2ll], alpha[2ll-1]) in log2 domain
  int sE = 2 * ll;
  int sP = sE - 1 < 0 ? 0 : sE - 1;
  int laneA = sE >> 3, jA = sE & 7;
  int laneB = sP >> 3, jB = sP & 7;
  float va = a0;
  if (jA == 1) va = a1;
  if (jA == 2) va = a2;
  if (jA == 3) va = a3;
  if (jA == 4) va = a4;
  if (jA == 5) va = a5;
  if (jA == 6) va = a6;
  if (jA == 7) va = a7;
  float vb = a0;
  if (jB == 1) vb = a1;
  if (jB == 2) vb = a2;
  if (jB == 3) vb = a3;
  if (jB == 4) vb = a4;
  if (jB == 5) vb = a5;
  if (jB == 6) vb = a6;
  if (jB == 7) vb = a7;
  float aA = __int_as_float(__builtin_amdgcn_ds_bpermute(laneA << 2, __float_as_int(va)));
  float aB = __int_as_float(__builtin_amdgcn_ds_bpermute(laneB << 2, __float_as_int(vb)));
  int EA = __builtin_amdgcn_ds_bpermute(laneA << 2, E);
  int EB = __builtin_amdgcn_ds_bpermute(laneB << 2, E);
  if (lane == 0) {
    float l1 = (aA > 0.0f) ? (float)EA + log2f(aA) : -1e30f;
    float l2 = (aB > 0.0f) ? (float)EB + log2f(aB) : -1e30f;
    float mm = fmaxf(l1, l2);
    float v = mm + log2f(exp2f(l1 - mm) + exp2f(l2 - mm));
    out[b] = -v * LN2F;
  }
}

}  // namespace

extern "C" void kernel_launch(void* const* d_in, const int* in_sizes, int n_in,
                              void* d_out, int out_size, void* d_ws, size_t ws_size,
                              hipStream_t stream) {
  const float* y = (const float*)d_in[0];   // [64,2000,128] f32
  const int* yt = (const int*)d_in[1];      // [64,200] i32
  const int* il = (const int*)d_in[2];      // [64] i32
  const int* lb = (const int*)d_in[3];      // [64] i32
  float* out = (float*)d_out;               // [64] f32
  (void)d_ws; (void)ws_size;                // no workspace needed

  hipLaunchKernelGGL(ctc_fused_kernel, dim3(Bc), dim3(256), 0, stream,
                     y, yt, il, lb, out);
}